// Round 7
// baseline (520.384 us; speedup 1.0000x reference)
//
#include <hip/hip_runtime.h>
#include <hip/hip_bf16.h>
#include <cstddef>
#include <cstdint>

#define BATCH 8
#define SEQ   2048
#define DEMB  1024
#define DQ    512

typedef __attribute__((ext_vector_type(8))) _Float16 f16x8;
typedef __attribute__((ext_vector_type(4))) float f32x4;

#define MFMA16(a, b, c) __builtin_amdgcn_mfma_f32_16x16x32_f16((a), (b), (c), 0, 0, 0)

#define GLDS16(gp, lp) __builtin_amdgcn_global_load_lds(                      \
    (const __attribute__((address_space(1))) void*)(gp),                      \
    (__attribute__((address_space(3))) void*)(lp), 16, 0, 0)

#define VM_BAR(N)                                                             \
  asm volatile("s_waitcnt vmcnt(" #N ")\n\ts_barrier" ::: "memory")
#define VM_LGKM_BAR(N)                                                        \
  asm volatile("s_waitcnt vmcnt(" #N ") lgkmcnt(0)\n\ts_barrier" ::: "memory")

// ---------------------------------------------------------------------------
// Transpose W (fp32 [k][n]) -> WT (fp16 [n][k]) for all three weight mats.
// ---------------------------------------------------------------------------
__global__ __launch_bounds__(256) void wprep(
    const float* __restrict__ Wq, const float* __restrict__ Wk,
    const float* __restrict__ Wv, _Float16* __restrict__ wt)
{
  int qidx = blockIdx.x * 256 + threadIdx.x;     // 0 .. 3*1024*128-1
  int w   = qidx >> 17;
  int rem = qidx & 131071;
  int k   = rem >> 7;                            // 0..1023
  int n   = (rem & 127) * 4;                     // 0..508
  const float* W = (w == 0) ? Wq : (w == 1) ? Wk : Wv;
  float4 v = *(const float4*)&W[(size_t)k * DQ + n];
  _Float16* dst = wt + (size_t)w * (DQ * DEMB);
  dst[(size_t)(n + 0) * DEMB + k] = (_Float16)v.x;
  dst[(size_t)(n + 1) * DEMB + k] = (_Float16)v.y;
  dst[(size_t)(n + 2) * DEMB + k] = (_Float16)v.z;
  dst[(size_t)(n + 3) * DEMB + k] = (_Float16)v.w;
}

// ---------------------------------------------------------------------------
// Projection GEMM, single-pass fp16 MFMA. C[16384,512] = X[16384,1024]*W.
// Q packed into d_out in 32-ROW groups: group g = m>>5 occupies halfs
// [g*32768, (g+1)*32768): hi 32x512 then lo 32x512. This makes a 32-row
// flash block's output float range exactly overlay its own Q storage.
// ---------------------------------------------------------------------------
__global__ __launch_bounds__(256) void proj_f16(
    const float* __restrict__ x, const _Float16* __restrict__ wt,
    _Float16* __restrict__ kf, _Float16* __restrict__ vt,
    _Float16* __restrict__ qpack)
{
  const int w  = blockIdx.z;
  const int mt = blockIdx.y, nt = blockIdx.x;

  __shared__ _Float16 Xs[128][40];
  __shared__ _Float16 Ws[128][40];

  const int tid  = threadIdx.x;
  const int wave = tid >> 6, l = tid & 63;
  const int wm = wave >> 1, wn = wave & 1;
  const int lo4 = l & 15, hi2 = l >> 4;

  f32x4 acc[4][4];
  #pragma unroll
  for (int mf = 0; mf < 4; mf++)
    #pragma unroll
    for (int nf = 0; nf < 4; nf++)
      #pragma unroll
      for (int i = 0; i < 4; i++) acc[mf][nf][i] = 0.f;

  const int    srow  = tid >> 1;
  const int    skh   = (tid & 1) * 16;
  const size_t xbase = (size_t)(mt * 128 + srow) * DEMB + skh;
  const size_t wbase = (size_t)w * (DQ * DEMB) + (size_t)(nt * 128 + srow) * DEMB + skh;

  #pragma unroll 1
  for (int k0 = 0; k0 < DEMB; k0 += 32) {
    #pragma unroll
    for (int i = 0; i < 2; i++) {
      float4 t0 = *(const float4*)&x[xbase + k0 + i * 8];
      float4 t1 = *(const float4*)&x[xbase + k0 + i * 8 + 4];
      f16x8 hv;
      hv[0] = (_Float16)t0.x; hv[1] = (_Float16)t0.y;
      hv[2] = (_Float16)t0.z; hv[3] = (_Float16)t0.w;
      hv[4] = (_Float16)t1.x; hv[5] = (_Float16)t1.y;
      hv[6] = (_Float16)t1.z; hv[7] = (_Float16)t1.w;
      *(f16x8*)&Xs[srow][skh + i * 8] = hv;
    }
    *(f16x8*)&Ws[srow][skh]     = *(const f16x8*)&wt[wbase + k0];
    *(f16x8*)&Ws[srow][skh + 8] = *(const f16x8*)&wt[wbase + k0 + 8];
    __syncthreads();

    f16x8 a[4], bfr[4];
    #pragma unroll
    for (int mf = 0; mf < 4; mf++)
      a[mf] = *(const f16x8*)&Xs[wm*64 + mf*16 + lo4][hi2*8];
    #pragma unroll
    for (int nf = 0; nf < 4; nf++)
      bfr[nf] = *(const f16x8*)&Ws[wn*64 + nf*16 + lo4][hi2*8];
    #pragma unroll
    for (int mf = 0; mf < 4; mf++)
      #pragma unroll
      for (int nf = 0; nf < 4; nf++)
        acc[mf][nf] = MFMA16(a[mf], bfr[nf], acc[mf][nf]);
    __syncthreads();
  }

  const int mb = mt * 128 + wm * 64;
  const int nb = nt * 128 + wn * 64;
  #pragma unroll
  for (int mf = 0; mf < 4; mf++)
    #pragma unroll
    for (int nf = 0; nf < 4; nf++)
      #pragma unroll
      for (int i = 0; i < 4; i++) {
        int m = mb + mf*16 + hi2*4 + i;
        int n = nb + nf*16 + lo4;
        float val = acc[mf][nf][i];
        if (w == 0) {
          _Float16 h  = (_Float16)val;
          _Float16 lo = (_Float16)(val - (float)h);
          size_t base = (size_t)(m >> 5) * 32768 + (size_t)(m & 31) * 512 + n;
          qpack[base]         = h;
          qpack[base + 16384] = lo;
        } else if (w == 1) {
          kf[(size_t)m * 512 + n] = (_Float16)val;
        } else {
          vt[(size_t)(m >> 11) * (512 * 2048) + (size_t)n * 2048 + (m & 2047)]
              = (_Float16)val;
        }
      }
}

// ---------------------------------------------------------------------------
// Flash attention v5: v4's counted-vmcnt 4-phase pipeline, halved block.
// 256 threads = 4 waves; 32 q-rows/block; 32-key tiles (64 kt); grid 512 ->
// 2 independent blocks per CU (inter-block TLP fills barrier stalls).
// Wave roles: qw=w&1 -> 16 q-rows; kw=w>>1 -> 16-key half (QK) / d-interleave
// (PV). Q hi+lo in regs; mask in LDS; per-kt global traffic is exclusively
// global_load_lds -> exact vmcnt accounting (8/4/8+lgkm/4, as v4).
// ---------------------------------------------------------------------------
__global__ __launch_bounds__(256, 2) void flash_v5(
    const _Float16* __restrict__ kfp, const _Float16* __restrict__ vtp,
    const int* __restrict__ maskg,
    float* dout)                          // aliases Q storage - no restrict
{
  const int bb = blockIdx.x & 7;          // batch -> XCD pin
  const int qt = blockIdx.x >> 3;         // 0..63
  const int q0 = qt * 32;

  const int tid = threadIdx.x;
  const int w = tid >> 6, l = tid & 63;
  const int qw = w & 1;                   // 16-row group
  const int kw = w >> 1;                  // 0..1
  const int lo4 = l & 15, hi2 = l >> 4;

  __shared__ _Float16 Kst[2][32][256];    // 32KB, src-swizzled (512B rows)
  __shared__ _Float16 Vst[2][256][32];    // 32KB, src-swizzled (64B rows)
  __shared__ _Float16 P[32 * 32];         // 2KB, row-swizzled (64B rows)
  __shared__ int      Msk[2048];          // 8KB
  __shared__ float pmax[2][32], psum[2][32];

  const _Float16* qpk = (const _Float16*)dout + (size_t)(bb * 64 + qt) * 32768;
  const char*     kb  = (const char*)(kfp + (size_t)bb * SEQ * 512);
  const char*     vtb = (const char*)(vtp + (size_t)bb * (512 * 2048));

  const _Float16* qhi = qpk + (size_t)(qw * 16 + lo4) * 512;
  const _Float16* qlo = qhi + 16384;

  // K tile: 32 keys x 256 d-halfs = 16KB; 4 GLDS/thread.
#define STAGE_K(KT, H, B) do {                                                \
    const char* kg_ = kb + (size_t)(KT) * 32 * 1024;                          \
    char* lb_ = (char*)&Kst[(B)][0][0];                                       \
    _Pragma("unroll")                                                         \
    for (int i_ = 0; i_ < 4; i_++) {                                          \
      int D_ = i_ * 4096 + tid * 16;                                          \
      int row_ = D_ >> 9, cb_ = D_ & 511;                                     \
      GLDS16(kg_ + (size_t)row_ * 1024 + (H) * 512 +                          \
                 (cb_ ^ ((row_ & 7) << 4)),                                   \
             lb_ + D_);                                                       \
    } } while (0)

  // V tile: 256 d rows x 32 keys = 16KB; 64B rows -> swizzle (row&3)<<4.
#define STAGE_V(KT, H, B) do {                                                \
    const char* vg_ = vtb + (size_t)(KT) * 64;                                \
    char* lb_ = (char*)&Vst[(B)][0][0];                                       \
    _Pragma("unroll")                                                         \
    for (int i_ = 0; i_ < 4; i_++) {                                          \
      int D_ = i_ * 4096 + tid * 16;                                          \
      int row_ = D_ >> 6, cb_ = D_ & 63;                                      \
      GLDS16(vg_ + (size_t)((H) * 256 + row_) * 4096 +                        \
                 (cb_ ^ ((row_ & 3) << 4)),                                   \
             lb_ + D_);                                                       \
    } } while (0)

#define QK_HALF(H, B) do {                                                    \
    const char* kl_ = (const char*)&Kst[(B)][0][0];                           \
    const int r0_ = kw * 16 + lo4;                                            \
    const int sw_ = (r0_ & 7) << 4;                                           \
    __builtin_amdgcn_s_setprio(1);                                            \
    _Pragma("unroll")                                                         \
    for (int s_ = 0; s_ < 8; s_++) {                                          \
      const int dby_ = (s_ * 32 + hi2 * 8) * 2;                               \
      f16x8 k0 = *(const f16x8*)(kl_ + r0_ * 512 + (dby_ ^ sw_));             \
      S = MFMA16(fq[(H) * 8 + s_], k0, S);                                    \
      S = MFMA16(fql[(H) * 8 + s_], k0, S);                                   \
    }                                                                         \
    __builtin_amdgcn_s_setprio(0);                                            \
    } while (0)

  // PV d-half H: o frags d = H*256 + j*32 + kw*16 + [0,16)
#define PV_HALF(H, B) do {                                                    \
    const char* vl_ = (const char*)&Vst[(B)][0][0];                           \
    __builtin_amdgcn_s_setprio(1);                                            \
    _Pragma("unroll")                                                         \
    for (int j_ = 0; j_ < 8; j_++) {                                          \
      const int dl_ = j_ * 32 + kw * 16 + lo4;                                \
      f16x8 v0 = *(const f16x8*)(vl_ + dl_ * 64 +                             \
                                 ((hi2 * 16) ^ ((dl_ & 3) << 4)));            \
      o[(H) * 8 + j_] = MFMA16(pa, v0, o[(H) * 8 + j_]);                      \
    }                                                                         \
    __builtin_amdgcn_s_setprio(0);                                            \
    } while (0)

  // ---- prologue: mask -> LDS, Q hi+lo -> regs, stage kt0.h0, full drain ----
  {
    const int4* ms = (const int4*)&maskg[bb * SEQ];
    *(int4*)&Msk[tid * 8]     = ms[tid * 2];
    *(int4*)&Msk[tid * 8 + 4] = ms[tid * 2 + 1];
  }
  f16x8 fq[16], fql[16];
  #pragma unroll
  for (int st = 0; st < 16; st++) {
    fq[st]  = *(const f16x8*)(qhi + st * 32 + hi2 * 8);
    fql[st] = *(const f16x8*)(qlo + st * 32 + hi2 * 8);
  }
  STAGE_K(0, 0, 0);
  __syncthreads();                        // drains everything -> vmcnt 0

  f32x4 o[16];
  #pragma unroll
  for (int f = 0; f < 16; f++)
    #pragma unroll
    for (int i = 0; i < 4; i++) o[f][i] = 0.f;

  float m_run[4], l_run[4], m_runP = -3.0e38f;
  #pragma unroll
  for (int i = 0; i < 4; i++) { m_run[i] = -3.0e38f; l_run[i] = 0.f; }

  #pragma unroll 1
  for (int kt = 0; kt < 64; kt++) {
    const int key0 = kt * 32;

    // ---- P1: issue K.h1 + V.h0; publish Ks[0]; QK h0 ----
    STAGE_K(kt, 1, 1);                    // A
    STAGE_V(kt, 0, 0);                    // C
    VM_BAR(8);                            // drains E(prev) -> Ks[0] ready

    f32x4 S;
    #pragma unroll
    for (int i = 0; i < 4; i++) S[i] = 0.f;
    QK_HALF(0, 0);

    // ---- P2: publish Ks[1]; QK h1; issue V.h1 + K'.h0; local softmax ----
    VM_BAR(4);                            // drains A -> Ks[1] ready
    const int ms = Msk[key0 + kw * 16 + lo4];
    QK_HALF(1, 1);

    STAGE_V(kt, 1, 1);                    // D
    STAGE_K(kt + 1, 0, 0);                // E (kt=63 overruns into VT: benign)

    #pragma unroll
    for (int i = 0; i < 4; i++) {
      if (!ms) S[i] = -1.0e9f;
      float mx = S[i];
      #pragma unroll
      for (int off = 1; off < 16; off <<= 1)
        mx = fmaxf(mx, __shfl_xor(mx, off, 64));
      float p0 = __expf(S[i] - mx);
      int row = qw*16 + hi2*4 + i;
      int swz = (row & 3) << 4;
      int b0  = (row*64 + (kw*16 + lo4)*2) ^ swz;
      *(_Float16*)((char*)P + b0) = (_Float16)p0;
      float ps = p0;
      #pragma unroll
      for (int off = 1; off < 16; off <<= 1) ps += __shfl_xor(ps, off, 64);
      if (lo4 == 0) { pmax[kw][row] = mx; psum[kw][row] = ps; }
    }

    // ---- P3: publish Vst[0] + P + stats ----
    VM_LGKM_BAR(8);                       // drains C -> Vst[0]; lgkm -> P/stats

    // ---- P4: merge stats, rescale o, scaled pa; PV h0; publish Vst[1]; PV h1
    float oscale[4];
    #pragma unroll
    for (int i = 0; i < 4; i++) {
      int row = qw*16 + hi2*4 + i;
      float m0 = pmax[0][row], m1 = pmax[1][row];
      float s0 = psum[0][row], s1 = psum[1][row];
      float mn = fmaxf(m_run[i], fmaxf(m0, m1));
      oscale[i] = __expf(m_run[i] - mn);
      l_run[i] = l_run[i] * oscale[i]
               + __expf(m0 - mn) * s0 + __expf(m1 - mn) * s1;
      m_run[i] = mn;
    }
    #pragma unroll
    for (int f = 0; f < 16; f++)
      #pragma unroll
      for (int i = 0; i < 4; i++) o[f][i] *= oscale[i];

    f16x8 pa;
    {
      const int prow = qw*16 + lo4;
      float m0p = pmax[0][prow], m1p = pmax[1][prow];
      float mnp = fmaxf(m_runP, fmaxf(m0p, m1p));
      m_runP = mnp;
      // lane's pa keys: hi2<2 -> keys 0..15 (kw=0 norm), else 16..31 (kw=1)
      _Float16 c = (_Float16)__expf(((hi2 < 2) ? m0p : m1p) - mnp);
      const int psw = (prow & 3) << 4;
      pa = *(const f16x8*)((const char*)P + ((prow*64 + hi2*16) ^ psw));
      pa = pa * c;
    }

    PV_HALF(0, 0);
    VM_BAR(4);                            // drains D -> Vst[1] ready (E stays)
    PV_HALF(1, 1);
  }
#undef STAGE_K
#undef STAGE_V
#undef QK_HALF
#undef PV_HALF

  asm volatile("s_waitcnt vmcnt(0)" ::: "memory");

  // ---- epilogue: normalize and store (overwrites block's own Q region) ----
  #pragma unroll
  for (int i = 0; i < 4; i++) {
    float inv = 1.0f / l_run[i];
    int rowg = bb * SEQ + q0 + qw*16 + hi2*4 + i;
    #pragma unroll
    for (int h = 0; h < 2; h++)
      #pragma unroll
      for (int j = 0; j < 8; j++) {
        int d = h*256 + j*32 + kw*16 + lo4;
        dout[(size_t)rowg * 512 + d] = o[h*8 + j][i] * inv;
      }
  }
}

extern "C" void kernel_launch(void* const* d_in, const int* in_sizes, int n_in,
                              void* d_out, int out_size, void* d_ws, size_t ws_size,
                              hipStream_t stream)
{
  const float* x    = (const float*)d_in[0];
  const float* Wq   = (const float*)d_in[1];
  const float* Wk   = (const float*)d_in[2];
  const float* Wv   = (const float*)d_in[3];
  const int*   mask = (const int*)d_in[4];

  _Float16* wsh = (_Float16*)d_ws;
  _Float16* KF = wsh;                  //  8,388,608 halfs (K fp16 [b*t][d])
  _Float16* VT = wsh + 8388608;        //  8,388,608 halfs (V^T fp16 [b][d][t])
  _Float16* WT = wsh + 16777216;       //  1,572,864 halfs -> 36.7 MB total

  wprep<<<1536, 256, 0, stream>>>(Wq, Wk, Wv, WT);

  dim3 pgrid(4, 128, 3);
  proj_f16<<<pgrid, 256, 0, stream>>>(x, WT, KF, VT, (_Float16*)d_out);

  flash_v5<<<512, 256, 0, stream>>>(KF, VT, mask, (float*)d_out);
}